// Round 6
// baseline (2724.429 us; speedup 1.0000x reference)
//
#include <hip/hip_runtime.h>
#include <stdint.h>

#define B       256
#define DIN     700
#define T       250
#define H       1024
#define DOUT    20
#define NW_IN   11      // u64 words for 700 input bits
#define NW_INP  12      // padded
#define NW_H    16      // u64 words for 1024 hidden bits
#define NROWS   64000   // B*T
#define LSTRIDE 144     // input list entries per row (70 mean + 9 sigma, mult of 4)
#define HSTRIDE 168     // hidden list entries per row (~80 mean + ~9 sigma, mult of 4)
#define SLICE   16      // h per block in currents_slice
#define WSTR    17      // LDS floats per d-row (16 + 1 pad)
#define ZPAD1   (700 * WSTR * 4)     // LDS byte offset of zero row (47600)
#define OSTR    21      // WoT_p floats per h-row (20 + 1 pad)
#define ZP2     (1024 * OSTR * 4)    // byte offset of WoT_p zero row (86016)

typedef unsigned long long u64;
typedef unsigned int u32;
typedef float vfloat4 __attribute__((ext_vector_type(4)));

// ---------------- prep: padded-transpose W_out ----------------
// WoT_p[1025][21]: [h][o] = W_out[o][h] for h<1024,o<20; else 0 (pads + zero row)
__global__ void prep_wout(const float* __restrict__ W_out,
                          float* __restrict__ WoT_p) {
    int i = blockIdx.x * 256 + threadIdx.x;
    if (i >= 1025 * OSTR) return;
    int h = i / OSTR;
    int o = i - h * OSTR;
    WoT_p[i] = (h < H && o < DOUT) ? W_out[o * H + h] : 0.0f;
}

// ---------------- prep: bitpack spikes ----------------
__global__ void prep_bits(const float* __restrict__ spk,
                          u64* __restrict__ bits) {
    int b  = blockIdx.x >> 2;
    int wc = blockIdx.x & 3;
    int t  = threadIdx.x;
    if (t >= T) return;
    int w0 = wc * 3;
    int w1 = (wc == 3) ? NW_IN : w0 + 3;
    const float* base = spk + (size_t)b * DIN * T + t;
    for (int w = w0; w < w1; ++w) {
        u64 m = 0;
#pragma unroll
        for (int j = 0; j < 64; ++j) {
            int d = (w << 6) + j;
            if (d < DIN) {
                float x = base[(size_t)d * T];
                m |= (u64)(x > 0.5f) << j;
            }
        }
        bits[((size_t)b * T + t) * NW_INP + w] = m;
    }
}

// ---------------- expand: input bits -> LDS-byte-offset lists ----------------
// Entry = d * WSTR * 4 (pre-scaled LDS byte offset), ascending d; filled to
// LSTRIDE with zero-row offset (group-max loop bound requires full fill).
__global__ void __launch_bounds__(256)
expand_kernel(const u64* __restrict__ bits,
              u32* __restrict__ lists,
              u32* __restrict__ ncnt) {
    int wv   = threadIdx.x >> 6;
    int lane = threadIdx.x & 63;
    int row  = blockIdx.x * 4 + wv;          // 16000 blocks -> 64000 rows
    const u64* wp = bits + (size_t)row * NW_INP;
    u32* lp = lists + (size_t)row * LSTRIDE;

    u64 lmask = (lane == 63) ? 0x7fffffffffffffffull : ((1ull << lane) - 1ull);
    u32 base = 0;
#pragma unroll
    for (int w = 0; w < NW_IN; ++w) {
        u64 m = wp[w];
        if ((m >> lane) & 1ull) {
            u32 pos = base + (u32)__popcll(m & lmask);
            if (pos < LSTRIDE) lp[pos] = (u32)((w << 6) + lane) * (WSTR * 4);
        }
        base += (u32)__popcll(m);
    }
    u32 n = base < LSTRIDE ? base : LSTRIDE;
    for (u32 pos = n + lane; pos < LSTRIDE; pos += 64) lp[pos] = ZPAD1;
    if (lane == 0) ncnt[row] = n;
}

// ---------------- S1: input currents, LDS b128 delivery ----------------
// Block = 16-h slice (LDS 47.7 KB, 2 blocks/CU). Wave = 16 rows x 4 lanes x 4 h:
// per list entry ONE ds_read_b128 delivers 16 rows x 16 h = 1024 B.
// Ascending-d fp32 sum order per row (bit-exact); zero-row pads add +0.0.
__global__ void __launch_bounds__(1024)
currents_slice(const float* __restrict__ W_hid,
               const u32* __restrict__ lists,  // pre-offset to chunk
               const u32* __restrict__ ncnt,   // pre-offset to chunk
               float* __restrict__ I) {        // chunk-local [rows][1024]
    __shared__ float wlds[700 * WSTR + WSTR];  // 47,668 B

    int slice = blockIdx.x & 63;
    int chunk = blockIdx.x >> 6;
    int h0    = slice * SLICE;
    int tid   = threadIdx.x;

    // stage: coalesced global read, stride-17 LDS write (bank-hop +1, clean)
    const float* wsrc = W_hid + h0 * DIN;
    for (int i = tid; i < SLICE * DIN; i += 1024) {
        int j = i / DIN;
        int d = i - j * DIN;
        wlds[d * WSTR + j] = wsrc[i];
    }
    if (tid < WSTR) wlds[700 * WSTR + tid] = 0.0f;
    __syncthreads();

    const char* wb = (const char*)wlds;
    int wv   = tid >> 6;
    int lane = tid & 63;
    int g    = lane >> 2;          // 0..15: row within wave group
    int sb   = (lane & 3) << 4;    // h-quad byte offset within slice

    int rbase = chunk * 8000;

    for (int rg = wv; rg < 500; rg += 16) {
        int row = rbase + rg * 16 + g;
        int n = ncnt[row];
        int m1 = max(n,  __shfl_xor(n,  4));
        int m2 = max(m1, __shfl_xor(m1, 8));
        int m3 = max(m2, __shfl_xor(m2, 16));
        int mx = max(m3, __shfl_xor(m3, 32));
        int maxk = (mx + 3) & ~3;

        const u32* lp = lists + (size_t)row * LSTRIDE;
        vfloat4 acc = {0.0f, 0.0f, 0.0f, 0.0f};
        for (int k = 0; k < maxk; k += 4) {
            uint4 e = *(const uint4*)(lp + k);
            vfloat4 v0 = *(const vfloat4*)(wb + (e.x + sb));
            vfloat4 v1 = *(const vfloat4*)(wb + (e.y + sb));
            vfloat4 v2 = *(const vfloat4*)(wb + (e.z + sb));
            vfloat4 v3 = *(const vfloat4*)(wb + (e.w + sb));
            acc += v0; acc += v1; acc += v2; acc += v3;
        }
        __builtin_nontemporal_store(acc,
            (vfloat4*)(I + (size_t)row * H + h0 + ((lane & 3) << 2)));
    }
}

// ---------------- S2: hidden membrane scan + spike ballot ----------------
__global__ void __launch_bounds__(256)
scan_kernel(const float* __restrict__ I,      // chunk-local
            const float* __restrict__ hs0,    // pre-offset to chunk
            const float* __restrict__ hv0,    // pre-offset to chunk
            u64* __restrict__ hsbits) {       // pre-offset to chunk
    int b     = blockIdx.x >> 2;   // local b
    int slice = blockIdx.x & 3;
    int tid   = threadIdx.x;
    int wv    = tid >> 6;
    int lane  = tid & 63;
    int h     = slice * 256 + tid;

    float keep = hv0[b * H + h] * 0.5f * (1.0f - hs0[b * H + h]);
    const float* ip = I + (size_t)b * T * H + h;
    u64* hp = hsbits + (size_t)b * T * NW_H + slice * 4 + wv;

#pragma unroll 5
    for (int t = 0; t < T; ++t) {
        float v = keep + ip[(size_t)t * H];
        bool s = v > 0.5f;
        keep = s ? 0.0f : v * 0.5f;
        u64 bal = __ballot(s);
        if (lane == 0) hp[(size_t)t * NW_H] = bal;
    }
}

// ---------------- expand2: hidden bits -> WoT_p-byte-offset lists ----------------
// Entry = h * OSTR * 4, ascending h; padded (npad only) with ZP2.
__global__ void __launch_bounds__(256)
expand2_kernel(const u64* __restrict__ hsbits,
               u32* __restrict__ hlists,
               u32* __restrict__ hncnt) {
    int wv   = threadIdx.x >> 6;
    int lane = threadIdx.x & 63;
    int row  = blockIdx.x * 4 + wv;          // 16000 blocks -> 64000 rows
    const u64* wp = hsbits + (size_t)row * NW_H;
    u32* lp = hlists + (size_t)row * HSTRIDE;

    u64 lmask = (lane == 63) ? 0x7fffffffffffffffull : ((1ull << lane) - 1ull);
    u32 base = 0;
#pragma unroll
    for (int w = 0; w < NW_H; ++w) {
        u64 m = wp[w];
        if ((m >> lane) & 1ull) {
            u32 pos = base + (u32)__popcll(m & lmask);
            if (pos < HSTRIDE) lp[pos] = (u32)((w << 6) + lane) * (OSTR * 4);
        }
        base += (u32)__popcll(m);
    }
    u32 n = base < HSTRIDE ? base : HSTRIDE;
    u32 npad = (n + 3u) & ~3u;
    u32 p = n + lane;
    if (p < npad) lp[p] = ZP2;
    if (lane == 0) hncnt[row] = n;
}

// ---------------- output currents: 3 rows/wave, lane = 21*r + o ----------------
__global__ void __launch_bounds__(256)
out_currents(const u32* __restrict__ hlists,
             const u32* __restrict__ hncnt,
             const float* __restrict__ WoT_p,
             float* __restrict__ Iout) {
    int wv   = threadIdx.x >> 6;
    int lane = threadIdx.x & 63;
    int r    = lane / 21;            // 0..2 (lane 63 -> 3, idle)
    int o    = lane - r * 21;        // 0..20 (o==20 reads pad, not stored)
    if (r > 2) return;
    int row = blockIdx.x * 12 + wv * 3 + r;
    if (row >= NROWS) return;

    const char* wp = (const char*)WoT_p;
    int ob = o << 2;
    int n = hncnt[row];
    int maxk = (n + 3) & ~3;
    const u32* lp = hlists + (size_t)row * HSTRIDE;

    float acc = 0.0f;
    for (int k = 0; k < maxk; k += 4) {
        uint4 e = *(const uint4*)(lp + k);
        float v0 = *(const float*)(wp + (e.x + ob));
        float v1 = *(const float*)(wp + (e.y + ob));
        float v2 = *(const float*)(wp + (e.z + ob));
        float v3 = *(const float*)(wp + (e.w + ob));
        acc += v0; acc += v1; acc += v2; acc += v3;
    }
    if (o < DOUT) Iout[(size_t)row * DOUT + o] = acc;
}

// ---------------- output scan + spike count ----------------
__global__ void out_scan(const float* __restrict__ Iout,
                         const float* __restrict__ os0,
                         const float* __restrict__ ov0,
                         float* __restrict__ outp) {
    int idx = blockIdx.x * 256 + threadIdx.x;
    if (idx >= B * DOUT) return;
    int b = idx / DOUT;
    int o = idx - b * DOUT;

    float ov = ov0[idx];
    float os = os0[idx];
    float keep = ov * 0.5f * (1.0f - os);
    float cnt = 0.0f;
    const float* ip = Iout + (size_t)b * T * DOUT + o;
#pragma unroll 5
    for (int t = 0; t < T; ++t) {
        float v = keep + ip[(size_t)t * DOUT];
        float s = (v > 0.5f) ? 1.0f : 0.0f;
        cnt += s;
        keep = v * 0.5f * (1.0f - s);
    }
    outp[idx] = cnt;
}

extern "C" void kernel_launch(void* const* d_in, const int* in_sizes, int n_in,
                              void* d_out, int out_size, void* d_ws, size_t ws_size,
                              hipStream_t stream) {
    const float* spike = (const float*)d_in[0];   // [256][700][250]
    const float* W_hid = (const float*)d_in[1];   // [1024][700]
    const float* W_out = (const float*)d_in[2];   // [20][1024]
    const float* hs0   = (const float*)d_in[3];   // [256][1024]
    const float* hv0   = (const float*)d_in[4];
    const float* os0   = (const float*)d_in[5];   // [256][20]
    const float* ov0   = (const float*)d_in[6];
    float* outp = (float*)d_out;                  // [256][20]

    char* ws = (char*)d_ws;
    float* WoT_p  = (float*)(ws);                 // 1025*21*4 = 86,100 (region 90,112)
    u64*   bits   = (u64*)  (ws + 90112);         // 64000*12*8  = 6,144,000
    u32*   ncnt   = (u32*)  (ws + 6234112);       // 64000*4     =   256,000
    u32*   lists  = (u32*)  (ws + 6490112);       // 64000*144*4 = 36,864,000
    u64*   hsbits = (u64*)  (ws + 43354112);      // 64000*16*8  = 8,192,000
    u32*   hncnt  = (u32*)  (ws + 51546112);      // 64000*4     =   256,000
    float* Iout   = (float*)(ws + 51802112);      // 64000*20*4  = 5,120,000
    float* Ibuf   = (float*)(ws + 56922112);      // bchunk*250*1024*4
    // hlists aliases the dead bits+ncnt+lists region after the chunk loop:
    // 64000*168*4 = 43,008,000 <= 43,264,000 available from offset 90,112.
    u32*   hlists = (u32*)  (ws + 90112);

    int bchunk = 256;
    while (bchunk > 32 &&
           (size_t)56922112 + (size_t)bchunk * 1024000ull > ws_size)
        bchunk >>= 1;

    prep_wout<<<(1025 * OSTR + 255) / 256, 256, 0, stream>>>(W_out, WoT_p);
    prep_bits<<<1024, 256, 0, stream>>>(spike, bits);
    expand_kernel<<<16000, 256, 0, stream>>>(bits, lists, ncnt);

    for (int b0 = 0; b0 < B; b0 += bchunk) {
        int rows = bchunk * T;                     // multiple of 8000 for bchunk>=32
        currents_slice<<<64 * (rows / 8000), 1024, 0, stream>>>(
            W_hid,
            lists + (size_t)(b0 * T) * LSTRIDE,
            ncnt + (size_t)(b0 * T),
            Ibuf);
        scan_kernel<<<bchunk * 4, 256, 0, stream>>>(
            Ibuf, hs0 + (size_t)b0 * H, hv0 + (size_t)b0 * H,
            hsbits + (size_t)b0 * T * NW_H);
    }

    expand2_kernel<<<16000, 256, 0, stream>>>(hsbits, hlists, hncnt);
    out_currents<<<(NROWS + 11) / 12, 256, 0, stream>>>(hlists, hncnt, WoT_p, Iout);
    out_scan<<<20, 256, 0, stream>>>(Iout, os0, ov0, outp);
}

// Round 7
// 2717.602 us; speedup vs baseline: 1.0025x; 1.0025x over previous
//
#include <hip/hip_runtime.h>
#include <stdint.h>

#define B       256
#define DIN     700
#define T       250
#define H       1024
#define DOUT    20
#define NW_IN   11      // u64 words for 700 input bits
#define NW_INP  12      // padded
#define NW_H    16      // u64 words for 1024 hidden bits
#define NROWS   64000   // B*T
#define LSTRIDE 144     // input list entries per row (70 mean + 9 sigma, mult of 4)
#define HSTRIDE 168     // hidden list entries per row (~80 mean + ~9 sigma, mult of 4)
#define SLICE   16      // h per block in currents_slice
#define WSTR    17      // LDS floats per d-row (16 + 1 pad)
#define ZPAD1   (700 * WSTR * 4)     // LDS byte offset of zero row (47600)
#define OSTR    21      // WoT_p floats per h-row (20 + 1 pad)
#define ZP2     (1024 * OSTR * 4)    // byte offset of WoT_p zero row (86016)

typedef unsigned long long u64;
typedef unsigned int u32;
typedef float vfloat4 __attribute__((ext_vector_type(4)));

// ---------------- prep: padded-transpose W_out ----------------
__global__ void prep_wout(const float* __restrict__ W_out,
                          float* __restrict__ WoT_p) {
    int i = blockIdx.x * 256 + threadIdx.x;
    if (i >= 1025 * OSTR) return;
    int h = i / OSTR;
    int o = i - h * OSTR;
    WoT_p[i] = (h < H && o < DOUT) ? W_out[o * H + h] : 0.0f;
}

// ---------------- prep: bitpack spikes ----------------
__global__ void prep_bits(const float* __restrict__ spk,
                          u64* __restrict__ bits) {
    int b  = blockIdx.x >> 2;
    int wc = blockIdx.x & 3;
    int t  = threadIdx.x;
    if (t >= T) return;
    int w0 = wc * 3;
    int w1 = (wc == 3) ? NW_IN : w0 + 3;
    const float* base = spk + (size_t)b * DIN * T + t;
    for (int w = w0; w < w1; ++w) {
        u64 m = 0;
#pragma unroll
        for (int j = 0; j < 64; ++j) {
            int d = (w << 6) + j;
            if (d < DIN) {
                float x = base[(size_t)d * T];
                m |= (u64)(x > 0.5f) << j;
            }
        }
        bits[((size_t)b * T + t) * NW_INP + w] = m;
    }
}

// ---------------- expand: input bits -> LDS-byte-offset lists ----------------
__global__ void __launch_bounds__(256)
expand_kernel(const u64* __restrict__ bits,
              u32* __restrict__ lists,
              u32* __restrict__ ncnt) {
    int wv   = threadIdx.x >> 6;
    int lane = threadIdx.x & 63;
    int row  = blockIdx.x * 4 + wv;          // 16000 blocks -> 64000 rows
    const u64* wp = bits + (size_t)row * NW_INP;
    u32* lp = lists + (size_t)row * LSTRIDE;

    u64 lmask = (lane == 63) ? 0x7fffffffffffffffull : ((1ull << lane) - 1ull);
    u32 base = 0;
#pragma unroll
    for (int w = 0; w < NW_IN; ++w) {
        u64 m = wp[w];
        if ((m >> lane) & 1ull) {
            u32 pos = base + (u32)__popcll(m & lmask);
            if (pos < LSTRIDE) lp[pos] = (u32)((w << 6) + lane) * (WSTR * 4);
        }
        base += (u32)__popcll(m);
    }
    u32 n = base < LSTRIDE ? base : LSTRIDE;
    for (u32 pos = n + lane; pos < LSTRIDE; pos += 64) lp[pos] = ZPAD1;
    if (lane == 0) ncnt[row] = n;
}

// ---------------- S1: input currents, LDS b128 + depth-2 list prefetch ----------------
// Block = 16-h slice (LDS 47.7 KB, 2 blocks/CU = 32 waves). Wave = 16 rows x
// 4 lanes x 4 h; per list entry ONE ds_read_b128 delivers 16 rows x 16 h.
// Inner loop: consume e, prefetch lp[k+8] (always valid: list ZPAD-filled to
// LSTRIDE), rotate e<-f<-new. 4 ds_reads issued together before the adds.
// Ascending-d fp32 sum order per row (bit-exact); zero-row pads add +0.0.
__global__ void __launch_bounds__(1024, 8)
currents_slice(const float* __restrict__ W_hid,
               const u32* __restrict__ lists,  // pre-offset to chunk
               const u32* __restrict__ ncnt,   // pre-offset to chunk
               float* __restrict__ I) {        // chunk-local [rows][1024]
    __shared__ float wlds[700 * WSTR + WSTR];  // 47,668 B

    int slice = blockIdx.x & 63;
    int chunk = blockIdx.x >> 6;
    int h0    = slice * SLICE;
    int tid   = threadIdx.x;

    const float* wsrc = W_hid + h0 * DIN;
    for (int i = tid; i < SLICE * DIN; i += 1024) {
        int j = i / DIN;
        int d = i - j * DIN;
        wlds[d * WSTR + j] = wsrc[i];
    }
    if (tid < WSTR) wlds[700 * WSTR + tid] = 0.0f;
    __syncthreads();

    const char* wb = (const char*)wlds;
    int wv   = tid >> 6;
    int lane = tid & 63;
    int g    = lane >> 2;          // 0..15: row within wave group
    int sb   = (lane & 3) << 4;    // h-quad byte offset within slice

    int rbase = chunk * 8000;

    for (int rg = wv; rg < 500; rg += 16) {
        int row = rbase + rg * 16 + g;
        int n = ncnt[row];
        int m1 = max(n,  __shfl_xor(n,  4));
        int m2 = max(m1, __shfl_xor(m1, 8));
        int m3 = max(m2, __shfl_xor(m2, 16));
        int mx = max(m3, __shfl_xor(m3, 32));
        int maxk = (mx + 3) & ~3;

        const u32* lp = lists + (size_t)row * LSTRIDE;
        uint4 e = *(const uint4*)(lp);
        uint4 f = *(const uint4*)(lp + 4);
        vfloat4 acc = {0.0f, 0.0f, 0.0f, 0.0f};
        for (int k = 0; k < maxk; k += 4) {
            vfloat4 v0 = *(const vfloat4*)(wb + (e.x + sb));
            vfloat4 v1 = *(const vfloat4*)(wb + (e.y + sb));
            vfloat4 v2 = *(const vfloat4*)(wb + (e.z + sb));
            vfloat4 v3 = *(const vfloat4*)(wb + (e.w + sb));
            int kp = k + 8;
            kp = (kp > LSTRIDE - 4) ? (LSTRIDE - 4) : kp;
            uint4 en = *(const uint4*)(lp + kp);
            acc += v0; acc += v1; acc += v2; acc += v3;
            e = f; f = en;
        }
        __builtin_nontemporal_store(acc,
            (vfloat4*)(I + (size_t)row * H + h0 + ((lane & 3) << 2)));
    }
}

// ---------------- S2: hidden membrane scan + spike ballot ----------------
__global__ void __launch_bounds__(256)
scan_kernel(const float* __restrict__ I,      // chunk-local
            const float* __restrict__ hs0,    // pre-offset to chunk
            const float* __restrict__ hv0,    // pre-offset to chunk
            u64* __restrict__ hsbits) {       // pre-offset to chunk
    int b     = blockIdx.x >> 2;   // local b
    int slice = blockIdx.x & 3;
    int tid   = threadIdx.x;
    int wv    = tid >> 6;
    int lane  = tid & 63;
    int h     = slice * 256 + tid;

    float keep = hv0[b * H + h] * 0.5f * (1.0f - hs0[b * H + h]);
    const float* ip = I + (size_t)b * T * H + h;
    u64* hp = hsbits + (size_t)b * T * NW_H + slice * 4 + wv;

#pragma unroll 5
    for (int t = 0; t < T; ++t) {
        float v = keep + ip[(size_t)t * H];
        bool s = v > 0.5f;
        keep = s ? 0.0f : v * 0.5f;
        u64 bal = __ballot(s);
        if (lane == 0) hp[(size_t)t * NW_H] = bal;
    }
}

// ---------------- expand2: hidden bits -> WoT_p-byte-offset lists ----------------
__global__ void __launch_bounds__(256)
expand2_kernel(const u64* __restrict__ hsbits,
               u32* __restrict__ hlists,
               u32* __restrict__ hncnt) {
    int wv   = threadIdx.x >> 6;
    int lane = threadIdx.x & 63;
    int row  = blockIdx.x * 4 + wv;          // 16000 blocks -> 64000 rows
    const u64* wp = hsbits + (size_t)row * NW_H;
    u32* lp = hlists + (size_t)row * HSTRIDE;

    u64 lmask = (lane == 63) ? 0x7fffffffffffffffull : ((1ull << lane) - 1ull);
    u32 base = 0;
#pragma unroll
    for (int w = 0; w < NW_H; ++w) {
        u64 m = wp[w];
        if ((m >> lane) & 1ull) {
            u32 pos = base + (u32)__popcll(m & lmask);
            if (pos < HSTRIDE) lp[pos] = (u32)((w << 6) + lane) * (OSTR * 4);
        }
        base += (u32)__popcll(m);
    }
    u32 n = base < HSTRIDE ? base : HSTRIDE;
    u32 npad = (n + 3u) & ~3u;
    u32 p = n + lane;
    if (p < npad) lp[p] = ZP2;
    if (lane == 0) hncnt[row] = n;
}

// ---------------- output currents: 3 rows/wave, lane = 21*r + o ----------------
__global__ void __launch_bounds__(256)
out_currents(const u32* __restrict__ hlists,
             const u32* __restrict__ hncnt,
             const float* __restrict__ WoT_p,
             float* __restrict__ Iout) {
    int wv   = threadIdx.x >> 6;
    int lane = threadIdx.x & 63;
    int r    = lane / 21;            // 0..2 (lane 63 -> 3, idle)
    int o    = lane - r * 21;        // 0..20 (o==20 reads pad, not stored)
    if (r > 2) return;
    int row = blockIdx.x * 12 + wv * 3 + r;
    if (row >= NROWS) return;

    const char* wp = (const char*)WoT_p;
    int ob = o << 2;
    int n = hncnt[row];
    int maxk = (n + 3) & ~3;
    const u32* lp = hlists + (size_t)row * HSTRIDE;

    float acc = 0.0f;
    for (int k = 0; k < maxk; k += 4) {
        uint4 e = *(const uint4*)(lp + k);
        float v0 = *(const float*)(wp + (e.x + ob));
        float v1 = *(const float*)(wp + (e.y + ob));
        float v2 = *(const float*)(wp + (e.z + ob));
        float v3 = *(const float*)(wp + (e.w + ob));
        acc += v0; acc += v1; acc += v2; acc += v3;
    }
    if (o < DOUT) Iout[(size_t)row * DOUT + o] = acc;
}

// ---------------- output scan + spike count ----------------
__global__ void out_scan(const float* __restrict__ Iout,
                         const float* __restrict__ os0,
                         const float* __restrict__ ov0,
                         float* __restrict__ outp) {
    int idx = blockIdx.x * 256 + threadIdx.x;
    if (idx >= B * DOUT) return;
    int b = idx / DOUT;
    int o = idx - b * DOUT;

    float ov = ov0[idx];
    float os = os0[idx];
    float keep = ov * 0.5f * (1.0f - os);
    float cnt = 0.0f;
    const float* ip = Iout + (size_t)b * T * DOUT + o;
#pragma unroll 5
    for (int t = 0; t < T; ++t) {
        float v = keep + ip[(size_t)t * DOUT];
        float s = (v > 0.5f) ? 1.0f : 0.0f;
        cnt += s;
        keep = v * 0.5f * (1.0f - s);
    }
    outp[idx] = cnt;
}

extern "C" void kernel_launch(void* const* d_in, const int* in_sizes, int n_in,
                              void* d_out, int out_size, void* d_ws, size_t ws_size,
                              hipStream_t stream) {
    const float* spike = (const float*)d_in[0];   // [256][700][250]
    const float* W_hid = (const float*)d_in[1];   // [1024][700]
    const float* W_out = (const float*)d_in[2];   // [20][1024]
    const float* hs0   = (const float*)d_in[3];   // [256][1024]
    const float* hv0   = (const float*)d_in[4];
    const float* os0   = (const float*)d_in[5];   // [256][20]
    const float* ov0   = (const float*)d_in[6];
    float* outp = (float*)d_out;                  // [256][20]

    char* ws = (char*)d_ws;
    float* WoT_p  = (float*)(ws);                 // 1025*21*4 = 86,100 (region 90,112)
    u64*   bits   = (u64*)  (ws + 90112);         // 64000*12*8  = 6,144,000
    u32*   ncnt   = (u32*)  (ws + 6234112);       // 64000*4     =   256,000
    u32*   lists  = (u32*)  (ws + 6490112);       // 64000*144*4 = 36,864,000
    u64*   hsbits = (u64*)  (ws + 43354112);      // 64000*16*8  = 8,192,000
    u32*   hncnt  = (u32*)  (ws + 51546112);      // 64000*4     =   256,000
    float* Iout   = (float*)(ws + 51802112);      // 64000*20*4  = 5,120,000
    float* Ibuf   = (float*)(ws + 56922112);      // bchunk*250*1024*4
    // hlists aliases the dead bits+ncnt+lists region after the chunk loop:
    u32*   hlists = (u32*)  (ws + 90112);

    int bchunk = 256;
    while (bchunk > 32 &&
           (size_t)56922112 + (size_t)bchunk * 1024000ull > ws_size)
        bchunk >>= 1;

    prep_wout<<<(1025 * OSTR + 255) / 256, 256, 0, stream>>>(W_out, WoT_p);
    prep_bits<<<1024, 256, 0, stream>>>(spike, bits);
    expand_kernel<<<16000, 256, 0, stream>>>(bits, lists, ncnt);

    for (int b0 = 0; b0 < B; b0 += bchunk) {
        int rows = bchunk * T;                     // multiple of 8000 for bchunk>=32
        currents_slice<<<64 * (rows / 8000), 1024, 0, stream>>>(
            W_hid,
            lists + (size_t)(b0 * T) * LSTRIDE,
            ncnt + (size_t)(b0 * T),
            Ibuf);
        scan_kernel<<<bchunk * 4, 256, 0, stream>>>(
            Ibuf, hs0 + (size_t)b0 * H, hv0 + (size_t)b0 * H,
            hsbits + (size_t)b0 * T * NW_H);
    }

    expand2_kernel<<<16000, 256, 0, stream>>>(hsbits, hlists, hncnt);
    out_currents<<<(NROWS + 11) / 12, 256, 0, stream>>>(hlists, hncnt, WoT_p, Iout);
    out_scan<<<20, 256, 0, stream>>>(Iout, os0, ov0, outp);
}